// Round 7
// baseline (175.521 us; speedup 1.0000x reference)
//
#include <hip/hip_runtime.h>
#include <math.h>

// Attention_msa_TwoStream. Only v_cls (d_in[1]) feeds outputs (MLP/q/k dead).
// N=3200, H=8, d=64, C=512; fp32 I/O; bf16 MFMA internals.
// R = (1/8) vnfull.vnfull^T is SYMMETRIC -> triangle tiles, pass1 Z/E sums,
// pass2 recomputes R and writes out2 directly (no Rg intermediate).
// X_h = vn_h.G_h - block-zone correction, G_h = vn_h^T V_h (64x64, built in k_prep).

#define NN 3200
#define HEADS 8
#define DH 64
#define CC 512
#define TT 50                 // NN/64 tile rows
#define NTRI 1275             // TT*(TT+1)/2

typedef __attribute__((ext_vector_type(8))) short short8;   // 8 bf16
typedef __attribute__((ext_vector_type(4))) float f32x4;

static __device__ __forceinline__ unsigned short f2b(float f) {
  union { float f; unsigned u; } x; x.f = f;
  unsigned r = x.u + 0x7FFFu + ((x.u >> 16) & 1u);   // RTN-even
  return (unsigned short)(r >> 16);
}
static __device__ __forceinline__ short8 pack8(f32x4 lo, f32x4 hi) {
  short8 r;
  r[0] = (short)f2b(lo[0]); r[1] = (short)f2b(lo[1]);
  r[2] = (short)f2b(lo[2]); r[3] = (short)f2b(lo[3]);
  r[4] = (short)f2b(hi[0]); r[5] = (short)f2b(hi[1]);
  r[6] = (short)f2b(hi[2]); r[7] = (short)f2b(hi[3]);
  return r;
}

typedef const void __attribute__((address_space(1))) gvoid_t;
typedef void __attribute__((address_space(3))) lvoid_t;
static __device__ __forceinline__ void gl_lds16(const void* g, void* l) {
  __builtin_amdgcn_global_load_lds((gvoid_t*)g, (lvoid_t*)l, 16, 0, 0);
}

// triangle decode: p -> (ti, tj), offset(a) = a*(101-a)/2
static __device__ __forceinline__ void tri_decode(int p, int& ti, int& tj) {
  int t = (int)((101.0 - sqrt(10201.0 - 8.0 * (double)p)) * 0.5);
  while (t * (101 - t) / 2 > p) t--;
  while ((t + 1) * (100 - t) / 2 <= p) t++;
  ti = t;
  tj = t + (p - t * (101 - t) / 2);
}

// ---------------------------------------------------------------------------
// Shared 64x64xK=512 Gram tile core. Swizzled LDS layout (8-row groups:
// slot = g*64 + kc*8 + r): staging is lane-linear (global_load_lds legal),
// global reads coalesce as 8x128B, frag ds_read_b128 is conflict-free.
static __device__ __forceinline__ void gram64(const unsigned short* __restrict__ vnfull,
                                              int n0, int m0,
                                              unsigned short (&As)[2][4096],
                                              unsigned short (&Bs)[2][4096],
                                              f32x4 (&acc)[2][2]) {
  int tid = threadIdx.x;
  int wv = tid >> 6, wr = wv >> 1, wc = wv & 1;
  int lane = tid & 63, quad = lane >> 4, l16 = lane & 15;
  int s0 = tid, s1 = tid + 256;
  int row0 = ((s0 >> 6) << 3) | (s0 & 7), kc0 = (s0 >> 3) & 7;
  int row1 = ((s1 >> 6) << 3) | (s1 & 7), kc1 = (s1 >> 3) & 7;
  const unsigned short* a0 = vnfull + (size_t)(n0 + row0) * CC + kc0 * 8;
  const unsigned short* a1 = vnfull + (size_t)(n0 + row1) * CC + kc1 * 8;
  const unsigned short* b0 = vnfull + (size_t)(m0 + row0) * CC + kc0 * 8;
  const unsigned short* b1 = vnfull + (size_t)(m0 + row1) * CC + kc1 * 8;

  int roA[2], roB[2];
  #pragma unroll
  for (int rt = 0; rt < 2; rt++) {
    int row = wr * 32 + rt * 16 + l16;
    roA[rt] = (row >> 3) * 512 + (row & 7) * 8;
  }
  #pragma unroll
  for (int ct = 0; ct < 2; ct++) {
    int row = wc * 32 + ct * 16 + l16;
    roB[ct] = (row >> 3) * 512 + (row & 7) * 8;
  }

  #pragma unroll
  for (int rt = 0; rt < 2; rt++)
    #pragma unroll
    for (int ct = 0; ct < 2; ct++) acc[rt][ct] = (f32x4){0.f, 0.f, 0.f, 0.f};

  gl_lds16(a0, &As[0][s0 * 8]); gl_lds16(a1, &As[0][s1 * 8]);
  gl_lds16(b0, &Bs[0][s0 * 8]); gl_lds16(b1, &Bs[0][s1 * 8]);
  __syncthreads();

  #pragma unroll 1
  for (int kk = 0; kk < 8; kk++) {
    int buf = kk & 1;
    if (kk < 7) {
      int ko = (kk + 1) * 64;
      gl_lds16(a0 + ko, &As[buf ^ 1][s0 * 8]); gl_lds16(a1 + ko, &As[buf ^ 1][s1 * 8]);
      gl_lds16(b0 + ko, &Bs[buf ^ 1][s0 * 8]); gl_lds16(b1 + ko, &Bs[buf ^ 1][s1 * 8]);
    }
    short8 af[2][2], bf[2][2];
    #pragma unroll
    for (int rt = 0; rt < 2; rt++)
      #pragma unroll
      for (int kh = 0; kh < 2; kh++)
        af[rt][kh] = *(const short8*)&As[buf][roA[rt] + (kh * 4 + quad) * 64];
    #pragma unroll
    for (int ct = 0; ct < 2; ct++)
      #pragma unroll
      for (int kh = 0; kh < 2; kh++)
        bf[ct][kh] = *(const short8*)&Bs[buf][roB[ct] + (kh * 4 + quad) * 64];
    #pragma unroll
    for (int kh = 0; kh < 2; kh++)
      #pragma unroll
      for (int rt = 0; rt < 2; rt++)
        #pragma unroll
        for (int ct = 0; ct < 2; ct++)
          acc[rt][ct] = __builtin_amdgcn_mfma_f32_16x16x32_bf16(af[rt][kh], bf[ct][kh],
                                                                acc[rt][ct], 0, 0, 0);
    __syncthreads();
  }
}

// ---------------------------------------------------------------------------
// k_prep: per-(n,h) L2 norm; writes vnfull bf16, vT[h][d][n] bf16, x_ori (f32),
// and accumulates G_h = vn_h^T V_h (contraction over this block's 64 rows)
// via MFMA from the LDS tiles + atomics.
__global__ __launch_bounds__(256) void k_prep(const float* __restrict__ v,
                                              unsigned short* __restrict__ vnfull,
                                              unsigned short* __restrict__ vT,
                                              float* __restrict__ Gf,
                                              float* __restrict__ out) {
  __shared__ unsigned short tileV[DH][72];   // [dim][row], stride 144B: 16B-aligned
  __shared__ unsigned short tileN[DH][72];
  int h  = blockIdx.x & 7;
  int n0 = (int)(blockIdx.x >> 3) * 64;
  int j  = threadIdx.x & 63;       // dim within head
  int w  = threadIdx.x >> 6;       // wave = row group
  #pragma unroll
  for (int i = 0; i < 16; i++) {
    int n = n0 + w * 16 + i;
    float val = v[(size_t)n * CC + h * DH + j];
    float ss = val * val;
    #pragma unroll
    for (int off = 32; off >= 1; off >>= 1) ss += __shfl_xor(ss, off, 64);
    float inv = 1.0f / (sqrtf(ss) + 1e-8f);
    unsigned short un = f2b(val * inv);
    tileV[j][w * 16 + i] = f2b(val);
    tileN[j][w * 16 + i] = un;
    vnfull[(size_t)n * CC + h * DH + j] = un;
    out[(size_t)n * (2 * CC) + CC + h * DH + j] = val;   // x_ori
  }
  __syncthreads();
  {
    int r = j;
    #pragma unroll
    for (int i = 0; i < 16; i++) {
      int jj = w * 16 + i;
      vT[((size_t)h * DH + jj) * NN + n0 + r] = tileV[jj][r];
    }
  }
  // G_h partial: G[d][k] += sum_{m in tile} V[m][d]*vn[m][k]
  int lane = threadIdx.x & 63, quad = lane >> 4, l16 = lane & 15;
  short8 aV[2];
  #pragma unroll
  for (int kh = 0; kh < 2; kh++)
    aV[kh] = *(const short8*)&tileV[w * 16 + l16][kh * 32 + quad * 8];
  #pragma unroll
  for (int ct = 0; ct < 4; ct++) {
    f32x4 g4 = (f32x4){0.f, 0.f, 0.f, 0.f};
    #pragma unroll
    for (int kh = 0; kh < 2; kh++) {
      short8 bN = *(const short8*)&tileN[ct * 16 + l16][kh * 32 + quad * 8];
      g4 = __builtin_amdgcn_mfma_f32_16x16x32_bf16(aV[kh], bN, g4, 0, 0, 0);
    }
    #pragma unroll
    for (int g = 0; g < 4; g++)
      atomicAdd(&Gf[(size_t)h * 4096 + (w * 16 + quad * 4 + g) * 64 + ct * 16 + l16], g4[g]);
  }
}

// ---------------------------------------------------------------------------
// k_zsum: pass 1 — triangle tiles, Z/E row sums only (no N^2 stores).
__global__ __launch_bounds__(256) void k_zsum(const unsigned short* __restrict__ vnfull,
                                              float* __restrict__ Zg,
                                              float* __restrict__ Eg) {
  __shared__ __align__(16) unsigned short As[2][4096];
  __shared__ __align__(16) unsigned short Bs[2][4096];
  int ti, tj;
  tri_decode((int)blockIdx.x, ti, tj);
  int n0 = ti * 64, m0 = tj * 64;
  bool diag = (ti == tj);
  f32x4 acc[2][2];
  gram64(vnfull, n0, m0, As, Bs, acc);

  int tid = threadIdx.x;
  int wv = tid >> 6, wr = wv >> 1, wc = wv & 1;
  int lane = tid & 63, quad = lane >> 4, l16 = lane & 15;
  int mloc[2], bs_col[2];
  #pragma unroll
  for (int ct = 0; ct < 2; ct++) {
    mloc[ct] = m0 + wc * 32 + ct * 16 + l16;
    bs_col[ct] = (mloc[ct] / 10) * 10;
  }
  float zcol[2] = {0.f, 0.f}, ecol[2] = {0.f, 0.f};
  #pragma unroll
  for (int rt = 0; rt < 2; rt++) {
    float zrow[4] = {0.f, 0.f, 0.f, 0.f}, erow[4] = {0.f, 0.f, 0.f, 0.f};
    #pragma unroll
    for (int g = 0; g < 4; g++) {
      int n = n0 + wr * 32 + rt * 16 + quad * 4 + g;
      int bs = (n / 10) * 10;
      #pragma unroll
      for (int ct = 0; ct < 2; ct++) {
        int m = mloc[ct];
        float R = acc[rt][ct][g] * 0.125f;
        float eR = __expf(R);
        bool sel = (R > 0.75f);
        bool zzf = (m >= bs) & (m < bs + 9) & (m != n);
        float ef = zzf ? 1.0f : eR;
        zrow[g] += ef;
        if (sel) erow[g] += ef;
        bool zzm = (n >= bs_col[ct]) & (n < bs_col[ct] + 9) & (n != m);
        float em = zzm ? 1.0f : eR;
        zcol[ct] += em;
        if (sel) ecol[ct] += em;
      }
    }
    #pragma unroll
    for (int g = 0; g < 4; g++) {
      float z = zrow[g], e = erow[g];
      #pragma unroll
      for (int off = 1; off <= 8; off <<= 1) {
        z += __shfl_xor(z, off, 64);
        e += __shfl_xor(e, off, 64);
      }
      if (l16 == 0) {
        int n = n0 + wr * 32 + rt * 16 + quad * 4 + g;
        atomicAdd(&Zg[n], z);
        atomicAdd(&Eg[n], e);
      }
    }
  }
  if (!diag) {
    #pragma unroll
    for (int ct = 0; ct < 2; ct++) {
      float z = zcol[ct], e = ecol[ct];
      z += __shfl_xor(z, 16, 64); z += __shfl_xor(z, 32, 64);
      e += __shfl_xor(e, 16, 64); e += __shfl_xor(e, 32, 64);
      if (quad == 0) {
        atomicAdd(&Zg[mloc[ct]], z);
        atomicAdd(&Eg[mloc[ct]], e);
      }
    }
  }
}

// ---------------------------------------------------------------------------
// k_out2: pass 2 — recompute triangle tiles (identical MFMA sequence -> bit-
// identical R), normalize with Z/E, write out2 forward + mirrored (f32).
__global__ __launch_bounds__(256) void k_out2(const unsigned short* __restrict__ vnfull,
                                              const float* __restrict__ Zg,
                                              const float* __restrict__ Eg,
                                              float* __restrict__ out2) {
  __shared__ __align__(16) unsigned short As[2][4096];
  __shared__ __align__(16) unsigned short Bs[2][4096];
  int ti, tj;
  tri_decode((int)blockIdx.x, ti, tj);
  int n0 = ti * 64, m0 = tj * 64;
  bool diag = (ti == tj);
  f32x4 acc[2][2];
  gram64(vnfull, n0, m0, As, Bs, acc);

  int tid = threadIdx.x;
  int wv = tid >> 6, wr = wv >> 1, wc = wv & 1;
  int lane = tid & 63, quad = lane >> 4, l16 = lane & 15;
  int mloc[2], bs_col[2];
  float rdc[2];
  #pragma unroll
  for (int ct = 0; ct < 2; ct++) {
    mloc[ct] = m0 + wc * 32 + ct * 16 + l16;
    bs_col[ct] = (mloc[ct] / 10) * 10;
    rdc[ct] = 1.0f / (Eg[mloc[ct]] + 1e-8f * Zg[mloc[ct]]);
  }
  #pragma unroll
  for (int rt = 0; rt < 2; rt++) {
    int nbase = n0 + wr * 32 + rt * 16 + quad * 4;
    float rdr[4];
    int bsr[4];
    #pragma unroll
    for (int g = 0; g < 4; g++) {
      int n = nbase + g;
      bsr[g] = (n / 10) * 10;
      rdr[g] = 1.0f / (Eg[n] + 1e-8f * Zg[n]);
    }
    #pragma unroll
    for (int ct = 0; ct < 2; ct++) {
      int m = mloc[ct];
      f32x4 mirv;
      #pragma unroll
      for (int g = 0; g < 4; g++) {
        int n = nbase + g;
        float R = acc[rt][ct][g] * 0.125f;
        float eR = __expf(R);
        bool sel = (R > 0.75f);
        bool zzf = (m >= bsr[g]) & (m < bsr[g] + 9) & (m != n);
        float ef = zzf ? 1.0f : eR;
        out2[(size_t)n * NN + m] = sel ? ef * rdr[g] : 0.f;
        bool zzm = (n >= bs_col[ct]) & (n < bs_col[ct] + 9) & (n != m);
        float em = zzm ? 1.0f : eR;
        mirv[g] = sel ? em * rdc[ct] : 0.f;
      }
      if (!diag)
        *(f32x4*)(out2 + (size_t)m * NN + nbase) = mirv;
    }
  }
}

// ---------------------------------------------------------------------------
// k_x: X_h[n][d] = sum_k vn[n][h*64+k]*G[h][k][d] - zone correction (MFMA w/
// masked-negated zone-S through LDS). 256 thr = 4 waves = 4 heads.
__global__ __launch_bounds__(256) void k_x(const unsigned short* __restrict__ vnfull,
                                           const float* __restrict__ Gf,
                                           const unsigned short* __restrict__ vT,
                                           float* __restrict__ out) {
  __shared__ __align__(16) unsigned short Sz[4][16][48];
  int hl   = threadIdx.x >> 6;                  // local head
  int h    = ((int)blockIdx.x & 1) * 4 + hl;
  int lane = threadIdx.x & 63;
  int quad = lane >> 4, l16 = lane & 15;
  int n0 = (int)(blockIdx.x >> 1) * 16;
  int lo = (n0 / 10) * 10;                      // zone window [lo, lo+32)

  short8 aZ[2];
  #pragma unroll
  for (int kh = 0; kh < 2; kh++)
    aZ[kh] = *(const short8*)(vnfull + (size_t)(n0 + l16) * CC + h * DH + kh * 32 + quad * 8);

  #pragma unroll
  for (int ct = 0; ct < 2; ct++) {
    int rB = lo + ct * 16 + l16;
    int rC = rB < NN ? rB : NN - 1;             // clamp OOB (mask kills it)
    short8 b0 = *(const short8*)(vnfull + (size_t)rC * CC + h * DH + quad * 8);
    short8 b1 = *(const short8*)(vnfull + (size_t)rC * CC + h * DH + 32 + quad * 8);
    f32x4 cS = (f32x4){0.f, 0.f, 0.f, 0.f};
    cS = __builtin_amdgcn_mfma_f32_16x16x32_bf16(aZ[0], b0, cS, 0, 0, 0);
    cS = __builtin_amdgcn_mfma_f32_16x16x32_bf16(aZ[1], b1, cS, 0, 0, 0);
    int m = lo + ct * 16 + l16;
    #pragma unroll
    for (int g = 0; g < 4; g++) {
      int n = n0 + quad * 4 + g;
      int bs = (n / 10) * 10;
      bool keep = (m >= bs) & (m < bs + 9) & (m != n);
      Sz[hl][quad * 4 + g][ct * 16 + l16] = f2b(keep ? -cS[g] : 0.f);
    }
  }
  __syncthreads();

  f32x4 xr[4];
  #pragma unroll
  for (int nt = 0; nt < 4; nt++) {
    const float* gp = Gf + (size_t)h * 4096 + (nt * 16 + l16) * 64 + quad * 8;
    short8 g0 = pack8(*(const f32x4*)gp, *(const f32x4*)(gp + 4));
    short8 g1 = pack8(*(const f32x4*)(gp + 32), *(const f32x4*)(gp + 36));
    f32x4 cX = (f32x4){0.f, 0.f, 0.f, 0.f};
    cX = __builtin_amdgcn_mfma_f32_16x16x32_bf16(aZ[0], g0, cX, 0, 0, 0);
    cX = __builtin_amdgcn_mfma_f32_16x16x32_bf16(aZ[1], g1, cX, 0, 0, 0);
    xr[nt] = cX;
  }

  short8 aC = *(const short8*)&Sz[hl][l16][quad * 8];
  #pragma unroll
  for (int nt = 0; nt < 4; nt++) {
    short8 b = *(const short8*)(vT + (size_t)(h * DH + nt * 16 + l16) * NN + lo + quad * 8);
    xr[nt] = __builtin_amdgcn_mfma_f32_16x16x32_bf16(aC, b, xr[nt], 0, 0, 0);
  }

  #pragma unroll
  for (int nt = 0; nt < 4; nt++)
    #pragma unroll
    for (int g = 0; g < 4; g++)
      out[(size_t)(n0 + quad * 4 + g) * (2 * CC) + h * DH + nt * 16 + l16] = xr[nt][g];
}

// ---------------------------------------------------------------------------
extern "C" void kernel_launch(void* const* d_in, const int* in_sizes, int n_in,
                              void* d_out, int out_size, void* d_ws, size_t ws_size,
                              hipStream_t stream) {
  const float* v = (const float*)d_in[1];   // only live input
  float* out = (float*)d_out;

  // ws carve (~6.7 MB): [Zg][Eg][Gf] f32, [vnfull][vT] bf16
  float* Zg = (float*)d_ws;
  float* Eg = Zg + NN;
  float* Gf = Eg + NN;
  unsigned short* vnfull = (unsigned short*)(Gf + HEADS * DH * DH);
  unsigned short* vT = vnfull + (size_t)NN * CC;

  hipMemsetAsync(d_ws, 0, (2 * NN + HEADS * DH * DH) * sizeof(float), stream);
  k_prep<<<dim3(HEADS * (NN / 64)), dim3(256), 0, stream>>>(v, vnfull, vT, Gf, out);
  k_zsum<<<dim3(NTRI), dim3(256), 0, stream>>>(vnfull, Zg, Eg);
  k_out2<<<dim3(NTRI), dim3(256), 0, stream>>>(vnfull, Zg, Eg, out + (size_t)NN * 2 * CC);
  k_x<<<dim3((NN / 16) * 2), dim3(256), 0, stream>>>(vnfull, Gf, vT, out);
}

// Round 8
// 161.668 us; speedup vs baseline: 1.0857x; 1.0857x over previous
//
#include <hip/hip_runtime.h>

// Attention_msa_TwoStream. Only v_cls (d_in[1]) feeds outputs (MLP/q/k dead).
// N=3200, H=8, d=64, C=512; fp32 I/O; bf16 MFMA internals.
// Pipeline: k_prep (norms + vT + x_ori + G_h accum) -> k_rgemm (R=1/8 vn.vn^T,
// 128x128 tiles, signed-e bf16 Rg + Z/E) -> k_x (X = vn.G - zone corr) ->
// k_soft (normalize Rg -> out2).

#define NN 3200
#define HEADS 8
#define DH 64
#define CC 512

typedef __attribute__((ext_vector_type(8))) short short8;   // 8 bf16
typedef __attribute__((ext_vector_type(4))) float f32x4;

static __device__ __forceinline__ unsigned short f2b(float f) {
  union { float f; unsigned u; } x; x.f = f;
  unsigned r = x.u + 0x7FFFu + ((x.u >> 16) & 1u);   // RTN-even
  return (unsigned short)(r >> 16);
}
static __device__ __forceinline__ float b2f(unsigned short s) {
  union { unsigned u; float f; } x; x.u = ((unsigned)s) << 16; return x.f;
}
static __device__ __forceinline__ short8 pack8(f32x4 lo, f32x4 hi) {
  short8 r;
  r[0] = (short)f2b(lo[0]); r[1] = (short)f2b(lo[1]);
  r[2] = (short)f2b(lo[2]); r[3] = (short)f2b(lo[3]);
  r[4] = (short)f2b(hi[0]); r[5] = (short)f2b(hi[1]);
  r[6] = (short)f2b(hi[2]); r[7] = (short)f2b(hi[3]);
  return r;
}

typedef const void __attribute__((address_space(1))) gvoid_t;
typedef void __attribute__((address_space(3))) lvoid_t;
static __device__ __forceinline__ void gl_lds16(const void* g, void* l) {
  __builtin_amdgcn_global_load_lds((gvoid_t*)g, (lvoid_t*)l, 16, 0, 0);
}

// ---------------------------------------------------------------------------
// k_prep: per-(n,h) L2 norm; writes vnfull bf16, vT[h][d][n] bf16, x_ori (f32),
// and accumulates G_h = vn_h^T V_h via MFMA from the LDS tiles + atomics.
__global__ __launch_bounds__(256) void k_prep(const float* __restrict__ v,
                                              unsigned short* __restrict__ vnfull,
                                              unsigned short* __restrict__ vT,
                                              float* __restrict__ Gf,
                                              float* __restrict__ out) {
  __shared__ unsigned short tileV[DH][72];   // [dim][row]
  __shared__ unsigned short tileN[DH][72];
  int h  = blockIdx.x & 7;
  int n0 = (int)(blockIdx.x >> 3) * 64;
  int j  = threadIdx.x & 63;       // dim within head
  int w  = threadIdx.x >> 6;       // wave = row group
  #pragma unroll
  for (int i = 0; i < 16; i++) {
    int n = n0 + w * 16 + i;
    float val = v[(size_t)n * CC + h * DH + j];
    float ss = val * val;
    #pragma unroll
    for (int off = 32; off >= 1; off >>= 1) ss += __shfl_xor(ss, off, 64);
    float inv = 1.0f / (sqrtf(ss) + 1e-8f);
    unsigned short un = f2b(val * inv);
    tileV[j][w * 16 + i] = f2b(val);
    tileN[j][w * 16 + i] = un;
    vnfull[(size_t)n * CC + h * DH + j] = un;
    out[(size_t)n * (2 * CC) + CC + h * DH + j] = val;   // x_ori
  }
  __syncthreads();
  #pragma unroll
  for (int i = 0; i < 16; i++) {
    int jj = w * 16 + i;
    vT[((size_t)h * DH + jj) * NN + n0 + j] = tileV[jj][j];
  }
  // G_h partial: G[d][k] += sum_{m in tile} V[m][d]*vn[m][k]
  int lane = threadIdx.x & 63, quad = lane >> 4, l16 = lane & 15;
  short8 aV[2];
  #pragma unroll
  for (int kh = 0; kh < 2; kh++)
    aV[kh] = *(const short8*)&tileV[w * 16 + l16][kh * 32 + quad * 8];
  #pragma unroll
  for (int ct = 0; ct < 4; ct++) {
    f32x4 g4 = (f32x4){0.f, 0.f, 0.f, 0.f};
    #pragma unroll
    for (int kh = 0; kh < 2; kh++) {
      short8 bN = *(const short8*)&tileN[ct * 16 + l16][kh * 32 + quad * 8];
      g4 = __builtin_amdgcn_mfma_f32_16x16x32_bf16(aV[kh], bN, g4, 0, 0, 0);
    }
    #pragma unroll
    for (int g = 0; g < 4; g++)
      atomicAdd(&Gf[(size_t)h * 4096 + (w * 16 + quad * 4 + g) * 64 + ct * 16 + l16], g4[g]);
  }
}

// ---------------------------------------------------------------------------
// k_rgemm: R = (1/8) vnfull.vnfull^T, full square, 128x128 block tiles,
// BK=64 double-buffered global_load_lds staging with swizzled (bank-balanced)
// LDS layout. 4 waves of 64x64. Epilogue: e=exp(mask?0:R), Rg bf16 = sel?e:-e,
// Z/E row atomics. grid 625.
__global__ __launch_bounds__(256) void k_rgemm(const unsigned short* __restrict__ vnfull,
                                               unsigned short* __restrict__ Rg,
                                               float* __restrict__ Zg,
                                               float* __restrict__ Eg) {
  __shared__ __align__(16) unsigned short As[2][8192];   // 32 KB
  __shared__ __align__(16) unsigned short Bs[2][8192];   // 32 KB
  int bi = (int)blockIdx.x % 25, bj = (int)blockIdx.x / 25;
  int n0 = bi * 128, m0 = bj * 128;
  int tid = threadIdx.x;
  int wv = tid >> 6, wr = wv >> 1, wc = wv & 1;
  int lane = tid & 63, quad = lane >> 4, l16 = lane & 15;

  // staging: slot s -> (row = ((s>>6)<<3)|(s&7), kc = (s>>3)&7); lane-linear
  // LDS dest (required by global_load_lds), 8x128B coalesced global reads,
  // bank-balanced ds_read_b128 on the frag side.
  const unsigned short* aG[4];
  const unsigned short* bG[4];
  int sl[4];
  #pragma unroll
  for (int t = 0; t < 4; t++) {
    int s = tid + t * 256;
    sl[t] = s;
    int row = ((s >> 6) << 3) | (s & 7), kc = (s >> 3) & 7;
    aG[t] = vnfull + (size_t)(n0 + row) * CC + kc * 8;
    bG[t] = vnfull + (size_t)(m0 + row) * CC + kc * 8;
  }

  int roA[4], roB[4];
  #pragma unroll
  for (int rt = 0; rt < 4; rt++) {
    int row = wr * 64 + rt * 16 + l16;
    roA[rt] = (row >> 3) * 512 + (row & 7) * 8;
  }
  #pragma unroll
  for (int ct = 0; ct < 4; ct++) {
    int row = wc * 64 + ct * 16 + l16;
    roB[ct] = (row >> 3) * 512 + (row & 7) * 8;
  }

  f32x4 acc[4][4];
  #pragma unroll
  for (int rt = 0; rt < 4; rt++)
    #pragma unroll
    for (int ct = 0; ct < 4; ct++) acc[rt][ct] = (f32x4){0.f, 0.f, 0.f, 0.f};

  #pragma unroll
  for (int t = 0; t < 4; t++) gl_lds16(aG[t], &As[0][sl[t] * 8]);
  #pragma unroll
  for (int t = 0; t < 4; t++) gl_lds16(bG[t], &Bs[0][sl[t] * 8]);
  __syncthreads();

  #pragma unroll 1
  for (int kk = 0; kk < 8; kk++) {
    int buf = kk & 1;
    if (kk < 7) {
      int ko = (kk + 1) * 64;
      #pragma unroll
      for (int t = 0; t < 4; t++) gl_lds16(aG[t] + ko, &As[buf ^ 1][sl[t] * 8]);
      #pragma unroll
      for (int t = 0; t < 4; t++) gl_lds16(bG[t] + ko, &Bs[buf ^ 1][sl[t] * 8]);
    }
    short8 af[4][2], bf[4][2];
    #pragma unroll
    for (int rt = 0; rt < 4; rt++)
      #pragma unroll
      for (int kh = 0; kh < 2; kh++)
        af[rt][kh] = *(const short8*)&As[buf][roA[rt] + (kh * 4 + quad) * 64];
    #pragma unroll
    for (int ct = 0; ct < 4; ct++)
      #pragma unroll
      for (int kh = 0; kh < 2; kh++)
        bf[ct][kh] = *(const short8*)&Bs[buf][roB[ct] + (kh * 4 + quad) * 64];
    #pragma unroll
    for (int kh = 0; kh < 2; kh++)
      #pragma unroll
      for (int rt = 0; rt < 4; rt++)
        #pragma unroll
        for (int ct = 0; ct < 4; ct++)
          acc[rt][ct] = __builtin_amdgcn_mfma_f32_16x16x32_bf16(af[rt][kh], bf[ct][kh],
                                                                acc[rt][ct], 0, 0, 0);
    __syncthreads();
  }

  // ---- epilogue: signed-e store + Z/E row sums ---------------------------
  #pragma unroll
  for (int rt = 0; rt < 4; rt++) {
    int nbase = n0 + wr * 64 + rt * 16 + quad * 4;
    #pragma unroll
    for (int g = 0; g < 4; g++) {
      int n = nbase + g;
      int bs = (n / 10) * 10;
      float z = 0.f, e = 0.f;
      #pragma unroll
      for (int ct = 0; ct < 4; ct++) {
        int m = m0 + wc * 64 + ct * 16 + l16;
        float R = acc[rt][ct][g] * 0.125f;
        float eR = __expf(R);
        bool sel = (R > 0.75f);
        bool zz = (m >= bs) & (m < bs + 9) & (m != n);
        float ef = zz ? 1.0f : eR;            // exp(0)=1
        Rg[(size_t)n * NN + m] = f2b(sel ? ef : -ef);
        z += ef;
        if (sel) e += ef;
      }
      #pragma unroll
      for (int off = 1; off <= 8; off <<= 1) {
        z += __shfl_xor(z, off, 64);
        e += __shfl_xor(e, off, 64);
      }
      if (l16 == 0) {
        atomicAdd(&Zg[n], z);
        atomicAdd(&Eg[n], e);
      }
    }
  }
}

// ---------------------------------------------------------------------------
// k_x: X_h[n][d] = sum_k vn[n][h*64+k]*G[h][k][d] - zone correction (MFMA w/
// masked-negated zone-S through LDS). 256 thr = 4 waves = 4 heads.
__global__ __launch_bounds__(256) void k_x(const unsigned short* __restrict__ vnfull,
                                           const float* __restrict__ Gf,
                                           const unsigned short* __restrict__ vT,
                                           float* __restrict__ out) {
  __shared__ __align__(16) unsigned short Sz[4][16][48];
  int hl   = threadIdx.x >> 6;                  // local head
  int h    = ((int)blockIdx.x & 1) * 4 + hl;
  int lane = threadIdx.x & 63;
  int quad = lane >> 4, l16 = lane & 15;
  int n0 = (int)(blockIdx.x >> 1) * 16;
  int lo = (n0 / 10) * 10;                      // zone window [lo, lo+32)

  short8 aZ[2];
  #pragma unroll
  for (int kh = 0; kh < 2; kh++)
    aZ[kh] = *(const short8*)(vnfull + (size_t)(n0 + l16) * CC + h * DH + kh * 32 + quad * 8);

  #pragma unroll
  for (int ct = 0; ct < 2; ct++) {
    int rB = lo + ct * 16 + l16;
    int rC = rB < NN ? rB : NN - 1;             // clamp OOB (mask kills it)
    short8 b0 = *(const short8*)(vnfull + (size_t)rC * CC + h * DH + quad * 8);
    short8 b1 = *(const short8*)(vnfull + (size_t)rC * CC + h * DH + 32 + quad * 8);
    f32x4 cS = (f32x4){0.f, 0.f, 0.f, 0.f};
    cS = __builtin_amdgcn_mfma_f32_16x16x32_bf16(aZ[0], b0, cS, 0, 0, 0);
    cS = __builtin_amdgcn_mfma_f32_16x16x32_bf16(aZ[1], b1, cS, 0, 0, 0);
    int m = lo + ct * 16 + l16;
    #pragma unroll
    for (int g = 0; g < 4; g++) {
      int n = n0 + quad * 4 + g;
      int bs = (n / 10) * 10;
      bool keep = (m >= bs) & (m < bs + 9) & (m != n);
      Sz[hl][quad * 4 + g][ct * 16 + l16] = f2b(keep ? -cS[g] : 0.f);
    }
  }
  __syncthreads();

  f32x4 xr[4];
  #pragma unroll
  for (int nt = 0; nt < 4; nt++) {
    const float* gp = Gf + (size_t)h * 4096 + (nt * 16 + l16) * 64 + quad * 8;
    short8 g0 = pack8(*(const f32x4*)gp, *(const f32x4*)(gp + 4));
    short8 g1 = pack8(*(const f32x4*)(gp + 32), *(const f32x4*)(gp + 36));
    f32x4 cX = (f32x4){0.f, 0.f, 0.f, 0.f};
    cX = __builtin_amdgcn_mfma_f32_16x16x32_bf16(aZ[0], g0, cX, 0, 0, 0);
    cX = __builtin_amdgcn_mfma_f32_16x16x32_bf16(aZ[1], g1, cX, 0, 0, 0);
    xr[nt] = cX;
  }

  short8 aC = *(const short8*)&Sz[hl][l16][quad * 8];
  #pragma unroll
  for (int nt = 0; nt < 4; nt++) {
    short8 b = *(const short8*)(vT + (size_t)(h * DH + nt * 16 + l16) * NN + lo + quad * 8);
    xr[nt] = __builtin_amdgcn_mfma_f32_16x16x32_bf16(aC, b, xr[nt], 0, 0, 0);
  }

  #pragma unroll
  for (int nt = 0; nt < 4; nt++)
    #pragma unroll
    for (int g = 0; g < 4; g++)
      out[(size_t)(n0 + quad * 4 + g) * (2 * CC) + h * DH + nt * 16 + l16] = xr[nt][g];
}

// ---------------------------------------------------------------------------
// k_soft: out2[n][m] = s>0 ? s / (Esel + EPS*Z) : 0   (s = signed-e, bf16)
__global__ void k_soft(const unsigned short* __restrict__ Rg, const float* __restrict__ Zg,
                       const float* __restrict__ Eg, float* __restrict__ out2) {
  unsigned int base = (blockIdx.x * blockDim.x + threadIdx.x) * 8u;
  unsigned int n = base / NN;
  short8 s8 = *(const short8*)(Rg + (size_t)base);
  float rd = 1.0f / (Eg[n] + 1e-8f * Zg[n]);
  f32x4 o0, o1;
  #pragma unroll
  for (int j = 0; j < 4; j++) {
    float s = b2f((unsigned short)s8[j]);
    o0[j] = (s > 0.f) ? s * rd : 0.f;
    float t = b2f((unsigned short)s8[4 + j]);
    o1[j] = (t > 0.f) ? t * rd : 0.f;
  }
  *(f32x4*)(out2 + (size_t)base) = o0;
  *(f32x4*)(out2 + (size_t)base + 4) = o1;
}

// ---------------------------------------------------------------------------
extern "C" void kernel_launch(void* const* d_in, const int* in_sizes, int n_in,
                              void* d_out, int out_size, void* d_ws, size_t ws_size,
                              hipStream_t stream) {
  const float* v = (const float*)d_in[1];   // only live input
  float* out = (float*)d_out;

  // ws carve (~27.3 MB): [Zg][Eg][Gf] f32, [vnfull][vT] bf16, [Rg] bf16
  float* Zg = (float*)d_ws;
  float* Eg = Zg + NN;
  float* Gf = Eg + NN;
  unsigned short* vnfull = (unsigned short*)(Gf + HEADS * DH * DH);
  unsigned short* vT = vnfull + (size_t)NN * CC;
  unsigned short* Rg = vT + (size_t)NN * CC;

  hipMemsetAsync(d_ws, 0, (2 * NN + HEADS * DH * DH) * sizeof(float), stream);
  k_prep<<<dim3(HEADS * (NN / 64)), dim3(256), 0, stream>>>(v, vnfull, vT, Gf, out);
  k_rgemm<<<dim3(25 * 25), dim3(256), 0, stream>>>(vnfull, Rg, Zg, Eg);
  k_x<<<dim3((NN / 16) * 2), dim3(256), 0, stream>>>(vnfull, Gf, vT, out);
  k_soft<<<dim3(NN * NN / 2048), dim3(256), 0, stream>>>(Rg, Zg, Eg, out + (size_t)NN * 2 * CC);
}

// Round 9
// 154.731 us; speedup vs baseline: 1.1344x; 1.0448x over previous
//
#include <hip/hip_runtime.h>

// Attention_msa_TwoStream. Only v_cls (d_in[1]) feeds outputs (MLP/q/k dead).
// N=3200, H=8, d=64, C=512; fp32 I/O; bf16 MFMA internals.
// Pipeline: k_prep (norms + vT + x_ori + G_h accum) -> k_rgemm (R=1/8 vn.vn^T,
// 128x128 tiles BK=32 dbuf 32KB LDS -> 5 blocks/CU, signed-e bf16 Rg + Z/E)
// -> k_x (X = vn.G - zone corr) -> k_soft (normalize Rg -> out2).

#define NN 3200
#define HEADS 8
#define DH 64
#define CC 512

typedef __attribute__((ext_vector_type(8))) short short8;   // 8 bf16
typedef __attribute__((ext_vector_type(4))) float f32x4;

static __device__ __forceinline__ unsigned short f2b(float f) {
  union { float f; unsigned u; } x; x.f = f;
  unsigned r = x.u + 0x7FFFu + ((x.u >> 16) & 1u);   // RTN-even
  return (unsigned short)(r >> 16);
}
static __device__ __forceinline__ float b2f(unsigned short s) {
  union { unsigned u; float f; } x; x.u = ((unsigned)s) << 16; return x.f;
}
static __device__ __forceinline__ short8 pack8(f32x4 lo, f32x4 hi) {
  short8 r;
  r[0] = (short)f2b(lo[0]); r[1] = (short)f2b(lo[1]);
  r[2] = (short)f2b(lo[2]); r[3] = (short)f2b(lo[3]);
  r[4] = (short)f2b(hi[0]); r[5] = (short)f2b(hi[1]);
  r[6] = (short)f2b(hi[2]); r[7] = (short)f2b(hi[3]);
  return r;
}

typedef const void __attribute__((address_space(1))) gvoid_t;
typedef void __attribute__((address_space(3))) lvoid_t;
static __device__ __forceinline__ void gl_lds16(const void* g, void* l) {
  __builtin_amdgcn_global_load_lds((gvoid_t*)g, (lvoid_t*)l, 16, 0, 0);
}

// ---------------------------------------------------------------------------
// k_prep: per-(n,h) L2 norm; writes vnfull bf16, vT[h][d][n] bf16, x_ori (f32),
// and accumulates G_h = vn_h^T V_h via MFMA from the LDS tiles + atomics.
__global__ __launch_bounds__(256) void k_prep(const float* __restrict__ v,
                                              unsigned short* __restrict__ vnfull,
                                              unsigned short* __restrict__ vT,
                                              float* __restrict__ Gf,
                                              float* __restrict__ out) {
  __shared__ unsigned short tileV[DH][72];   // [dim][row]
  __shared__ unsigned short tileN[DH][72];
  int h  = blockIdx.x & 7;
  int n0 = (int)(blockIdx.x >> 3) * 64;
  int j  = threadIdx.x & 63;       // dim within head
  int w  = threadIdx.x >> 6;       // wave = row group
  #pragma unroll
  for (int i = 0; i < 16; i++) {
    int n = n0 + w * 16 + i;
    float val = v[(size_t)n * CC + h * DH + j];
    float ss = val * val;
    #pragma unroll
    for (int off = 32; off >= 1; off >>= 1) ss += __shfl_xor(ss, off, 64);
    float inv = 1.0f / (sqrtf(ss) + 1e-8f);
    unsigned short un = f2b(val * inv);
    tileV[j][w * 16 + i] = f2b(val);
    tileN[j][w * 16 + i] = un;
    vnfull[(size_t)n * CC + h * DH + j] = un;
    out[(size_t)n * (2 * CC) + CC + h * DH + j] = val;   // x_ori
  }
  __syncthreads();
  #pragma unroll
  for (int i = 0; i < 16; i++) {
    int jj = w * 16 + i;
    vT[((size_t)h * DH + jj) * NN + n0 + j] = tileV[jj][j];
  }
  // G_h partial: G[d][k] += sum_{m in tile} V[m][d]*vn[m][k]
  int lane = threadIdx.x & 63, quad = lane >> 4, l16 = lane & 15;
  short8 aV[2];
  #pragma unroll
  for (int kh = 0; kh < 2; kh++)
    aV[kh] = *(const short8*)&tileV[w * 16 + l16][kh * 32 + quad * 8];
  #pragma unroll
  for (int ct = 0; ct < 4; ct++) {
    f32x4 g4 = (f32x4){0.f, 0.f, 0.f, 0.f};
    #pragma unroll
    for (int kh = 0; kh < 2; kh++) {
      short8 bN = *(const short8*)&tileN[ct * 16 + l16][kh * 32 + quad * 8];
      g4 = __builtin_amdgcn_mfma_f32_16x16x32_bf16(aV[kh], bN, g4, 0, 0, 0);
    }
    #pragma unroll
    for (int g = 0; g < 4; g++)
      atomicAdd(&Gf[(size_t)h * 4096 + (w * 16 + quad * 4 + g) * 64 + ct * 16 + l16], g4[g]);
  }
}

// ---------------------------------------------------------------------------
// k_rgemm: R = (1/8) vnfull.vnfull^T, full square, 128x128 block tiles,
// BK=32 double-buffered global_load_lds staging (32 KB LDS -> 5 blocks/CU)
// with swizzled bank-balanced layout. 4 waves of 64x64.
// Epilogue: e=exp(mask?0:R), Rg bf16 = sel?e:-e, Z/E row atomics. grid 625.
__global__ __launch_bounds__(256) void k_rgemm(const unsigned short* __restrict__ vnfull,
                                               unsigned short* __restrict__ Rg,
                                               float* __restrict__ Zg,
                                               float* __restrict__ Eg) {
  __shared__ __align__(16) unsigned short As[2][4096];   // 16 KB (128 x 32 x2)
  __shared__ __align__(16) unsigned short Bs[2][4096];   // 16 KB
  int bi = (int)blockIdx.x % 25, bj = (int)blockIdx.x / 25;
  int n0 = bi * 128, m0 = bj * 128;
  int tid = threadIdx.x;
  int wv = tid >> 6, wr = wv >> 1, wc = wv & 1;
  int lane = tid & 63, quad = lane >> 4, l16 = lane & 15;

  // staging slot s in [0,512): row = ((s>>5)<<3)|(s&7), kc = (s>>3)&3.
  // LDS dest lane-linear (global_load_lds requirement); frag-side reads are
  // dense 1KB per 16-row group -> conflict-free.
  const unsigned short* aG[2];
  const unsigned short* bG[2];
  int sl[2];
  #pragma unroll
  for (int t = 0; t < 2; t++) {
    int s = tid + t * 256;
    sl[t] = s;
    int row = ((s >> 5) << 3) | (s & 7), kc = (s >> 3) & 3;
    aG[t] = vnfull + (size_t)(n0 + row) * CC + kc * 8;
    bG[t] = vnfull + (size_t)(m0 + row) * CC + kc * 8;
  }

  int roA[4], roB[4];
  #pragma unroll
  for (int rt = 0; rt < 4; rt++) {
    int row = wr * 64 + rt * 16 + l16;
    roA[rt] = (row >> 3) * 256 + (row & 7) * 8;
  }
  #pragma unroll
  for (int ct = 0; ct < 4; ct++) {
    int row = wc * 64 + ct * 16 + l16;
    roB[ct] = (row >> 3) * 256 + (row & 7) * 8;
  }

  f32x4 acc[4][4];
  #pragma unroll
  for (int rt = 0; rt < 4; rt++)
    #pragma unroll
    for (int ct = 0; ct < 4; ct++) acc[rt][ct] = (f32x4){0.f, 0.f, 0.f, 0.f};

  #pragma unroll
  for (int t = 0; t < 2; t++) gl_lds16(aG[t], &As[0][sl[t] * 8]);
  #pragma unroll
  for (int t = 0; t < 2; t++) gl_lds16(bG[t], &Bs[0][sl[t] * 8]);
  __syncthreads();

  #pragma unroll 1
  for (int kk = 0; kk < 16; kk++) {
    int buf = kk & 1;
    if (kk < 15) {
      int ko = (kk + 1) * 32;
      #pragma unroll
      for (int t = 0; t < 2; t++) gl_lds16(aG[t] + ko, &As[buf ^ 1][sl[t] * 8]);
      #pragma unroll
      for (int t = 0; t < 2; t++) gl_lds16(bG[t] + ko, &Bs[buf ^ 1][sl[t] * 8]);
    }
    short8 af[4], bf[4];
    #pragma unroll
    for (int rt = 0; rt < 4; rt++)
      af[rt] = *(const short8*)&As[buf][roA[rt] + quad * 64];
    #pragma unroll
    for (int ct = 0; ct < 4; ct++)
      bf[ct] = *(const short8*)&Bs[buf][roB[ct] + quad * 64];
    #pragma unroll
    for (int rt = 0; rt < 4; rt++)
      #pragma unroll
      for (int ct = 0; ct < 4; ct++)
        acc[rt][ct] = __builtin_amdgcn_mfma_f32_16x16x32_bf16(af[rt], bf[ct],
                                                              acc[rt][ct], 0, 0, 0);
    __syncthreads();
  }

  // ---- epilogue: signed-e store + Z/E row sums ---------------------------
  #pragma unroll
  for (int rt = 0; rt < 4; rt++) {
    int nbase = n0 + wr * 64 + rt * 16 + quad * 4;
    #pragma unroll
    for (int g = 0; g < 4; g++) {
      int n = nbase + g;
      int bs = (n / 10) * 10;
      float z = 0.f, e = 0.f;
      #pragma unroll
      for (int ct = 0; ct < 4; ct++) {
        int m = m0 + wc * 64 + ct * 16 + l16;
        float R = acc[rt][ct][g] * 0.125f;
        float eR = __expf(R);
        bool sel = (R > 0.75f);
        bool zz = (m >= bs) & (m < bs + 9) & (m != n);
        float ef = zz ? 1.0f : eR;            // exp(0)=1
        Rg[(size_t)n * NN + m] = f2b(sel ? ef : -ef);
        z += ef;
        if (sel) e += ef;
      }
      #pragma unroll
      for (int off = 1; off <= 8; off <<= 1) {
        z += __shfl_xor(z, off, 64);
        e += __shfl_xor(e, off, 64);
      }
      if (l16 == 0) {
        atomicAdd(&Zg[n], z);
        atomicAdd(&Eg[n], e);
      }
    }
  }
}

// ---------------------------------------------------------------------------
// k_x: X_h[n][d] = sum_k vn[n][h*64+k]*G[h][k][d] - zone correction (MFMA w/
// masked-negated zone-S through LDS). 256 thr = 4 waves = 4 heads.
__global__ __launch_bounds__(256) void k_x(const unsigned short* __restrict__ vnfull,
                                           const float* __restrict__ Gf,
                                           const unsigned short* __restrict__ vT,
                                           float* __restrict__ out) {
  __shared__ __align__(16) unsigned short Sz[4][16][48];
  int hl   = threadIdx.x >> 6;                  // local head
  int h    = ((int)blockIdx.x & 1) * 4 + hl;
  int lane = threadIdx.x & 63;
  int quad = lane >> 4, l16 = lane & 15;
  int n0 = (int)(blockIdx.x >> 1) * 16;
  int lo = (n0 / 10) * 10;                      // zone window [lo, lo+32)

  short8 aZ[2];
  #pragma unroll
  for (int kh = 0; kh < 2; kh++)
    aZ[kh] = *(const short8*)(vnfull + (size_t)(n0 + l16) * CC + h * DH + kh * 32 + quad * 8);

  #pragma unroll
  for (int ct = 0; ct < 2; ct++) {
    int rB = lo + ct * 16 + l16;
    int rC = rB < NN ? rB : NN - 1;             // clamp OOB (mask kills it)
    short8 b0 = *(const short8*)(vnfull + (size_t)rC * CC + h * DH + quad * 8);
    short8 b1 = *(const short8*)(vnfull + (size_t)rC * CC + h * DH + 32 + quad * 8);
    f32x4 cS = (f32x4){0.f, 0.f, 0.f, 0.f};
    cS = __builtin_amdgcn_mfma_f32_16x16x32_bf16(aZ[0], b0, cS, 0, 0, 0);
    cS = __builtin_amdgcn_mfma_f32_16x16x32_bf16(aZ[1], b1, cS, 0, 0, 0);
    int m = lo + ct * 16 + l16;
    #pragma unroll
    for (int g = 0; g < 4; g++) {
      int n = n0 + quad * 4 + g;
      int bs = (n / 10) * 10;
      bool keep = (m >= bs) & (m < bs + 9) & (m != n);
      Sz[hl][quad * 4 + g][ct * 16 + l16] = f2b(keep ? -cS[g] : 0.f);
    }
  }
  __syncthreads();

  f32x4 xr[4];
  #pragma unroll
  for (int nt = 0; nt < 4; nt++) {
    const float* gp = Gf + (size_t)h * 4096 + (nt * 16 + l16) * 64 + quad * 8;
    short8 g0 = pack8(*(const f32x4*)gp, *(const f32x4*)(gp + 4));
    short8 g1 = pack8(*(const f32x4*)(gp + 32), *(const f32x4*)(gp + 36));
    f32x4 cX = (f32x4){0.f, 0.f, 0.f, 0.f};
    cX = __builtin_amdgcn_mfma_f32_16x16x32_bf16(aZ[0], g0, cX, 0, 0, 0);
    cX = __builtin_amdgcn_mfma_f32_16x16x32_bf16(aZ[1], g1, cX, 0, 0, 0);
    xr[nt] = cX;
  }

  short8 aC = *(const short8*)&Sz[hl][l16][quad * 8];
  #pragma unroll
  for (int nt = 0; nt < 4; nt++) {
    short8 b = *(const short8*)(vT + (size_t)(h * DH + nt * 16 + l16) * NN + lo + quad * 8);
    xr[nt] = __builtin_amdgcn_mfma_f32_16x16x32_bf16(aC, b, xr[nt], 0, 0, 0);
  }

  #pragma unroll
  for (int nt = 0; nt < 4; nt++)
    #pragma unroll
    for (int g = 0; g < 4; g++)
      out[(size_t)(n0 + quad * 4 + g) * (2 * CC) + h * DH + nt * 16 + l16] = xr[nt][g];
}

// ---------------------------------------------------------------------------
// k_soft: out2[n][m] = s>0 ? s / (Esel + EPS*Z) : 0   (s = signed-e, bf16)
__global__ void k_soft(const unsigned short* __restrict__ Rg, const float* __restrict__ Zg,
                       const float* __restrict__ Eg, float* __restrict__ out2) {
  unsigned int base = (blockIdx.x * blockDim.x + threadIdx.x) * 8u;
  unsigned int n = base / NN;
  short8 s8 = *(const short8*)(Rg + (size_t)base);
  float rd = 1.0f / (Eg[n] + 1e-8f * Zg[n]);
  f32x4 o0, o1;
  #pragma unroll
  for (int j = 0; j < 4; j++) {
    float s = b2f((unsigned short)s8[j]);
    o0[j] = (s > 0.f) ? s * rd : 0.f;
    float t = b2f((unsigned short)s8[4 + j]);
    o1[j] = (t > 0.f) ? t * rd : 0.f;
  }
  *(f32x4*)(out2 + (size_t)base) = o0;
  *(f32x4*)(out2 + (size_t)base + 4) = o1;
}

// ---------------------------------------------------------------------------
extern "C" void kernel_launch(void* const* d_in, const int* in_sizes, int n_in,
                              void* d_out, int out_size, void* d_ws, size_t ws_size,
                              hipStream_t stream) {
  const float* v = (const float*)d_in[1];   // only live input
  float* out = (float*)d_out;

  // ws carve (~27.3 MB): [Zg][Eg][Gf] f32, [vnfull][vT] bf16, [Rg] bf16
  float* Zg = (float*)d_ws;
  float* Eg = Zg + NN;
  float* Gf = Eg + NN;
  unsigned short* vnfull = (unsigned short*)(Gf + HEADS * DH * DH);
  unsigned short* vT = vnfull + (size_t)NN * CC;
  unsigned short* Rg = vT + (size_t)NN * CC;

  hipMemsetAsync(d_ws, 0, (2 * NN + HEADS * DH * DH) * sizeof(float), stream);
  k_prep<<<dim3(HEADS * (NN / 64)), dim3(256), 0, stream>>>(v, vnfull, vT, Gf, out);
  k_rgemm<<<dim3(25 * 25), dim3(256), 0, stream>>>(vnfull, Rg, Zg, Eg);
  k_x<<<dim3((NN / 16) * 2), dim3(256), 0, stream>>>(vnfull, Gf, vT, out);
  k_soft<<<dim3(NN * NN / 2048), dim3(256), 0, stream>>>(Rg, Zg, Eg, out + (size_t)NN * 2 * CC);
}

// Round 10
// 149.469 us; speedup vs baseline: 1.1743x; 1.0352x over previous
//
#include <hip/hip_runtime.h>

// Attention_msa_TwoStream. Only v_cls (d_in[1]) feeds outputs (MLP/q/k dead).
// N=3200, H=8, d=64, C=512; fp32 I/O; bf16 MFMA internals.
// Pipeline (4 dispatches): memset(Gf) -> k_prep (norms + vT + x_ori + G_h)
// -> k_rgemm (R=1/8 vn.vn^T, 128x128 BK=32 dbuf, signed-e bf16 Rg, NT stores)
// -> k_fused (rows: Z/E row-sum + normalize -> out2 | tiles: X = vn.G - corr).
// Non-temporal stores keep the Rg/out2 streams from evicting vnfull out of L2.

#define NN 3200
#define HEADS 8
#define DH 64
#define CC 512

typedef __attribute__((ext_vector_type(8))) short short8;   // 8 bf16
typedef __attribute__((ext_vector_type(4))) float f32x4;

static __device__ __forceinline__ unsigned short f2b(float f) {
  union { float f; unsigned u; } x; x.f = f;
  unsigned r = x.u + 0x7FFFu + ((x.u >> 16) & 1u);   // RTN-even
  return (unsigned short)(r >> 16);
}
static __device__ __forceinline__ float b2f(unsigned short s) {
  union { unsigned u; float f; } x; x.u = ((unsigned)s) << 16; return x.f;
}
static __device__ __forceinline__ short8 pack8(f32x4 lo, f32x4 hi) {
  short8 r;
  r[0] = (short)f2b(lo[0]); r[1] = (short)f2b(lo[1]);
  r[2] = (short)f2b(lo[2]); r[3] = (short)f2b(lo[3]);
  r[4] = (short)f2b(hi[0]); r[5] = (short)f2b(hi[1]);
  r[6] = (short)f2b(hi[2]); r[7] = (short)f2b(hi[3]);
  return r;
}

typedef const void __attribute__((address_space(1))) gvoid_t;
typedef void __attribute__((address_space(3))) lvoid_t;
static __device__ __forceinline__ void gl_lds16(const void* g, void* l) {
  __builtin_amdgcn_global_load_lds((gvoid_t*)g, (lvoid_t*)l, 16, 0, 0);
}

// ---------------------------------------------------------------------------
// k_prep: per-(n,h) L2 norm; writes vnfull bf16 (cached - heavy reuse),
// vT bf16 + x_ori f32 (non-temporal - streaming), G_h accum via MFMA+atomics.
__global__ __launch_bounds__(256) void k_prep(const float* __restrict__ v,
                                              unsigned short* __restrict__ vnfull,
                                              unsigned short* __restrict__ vT,
                                              float* __restrict__ Gf,
                                              float* __restrict__ out) {
  __shared__ unsigned short tileV[DH][72];   // [dim][row]
  __shared__ unsigned short tileN[DH][72];
  int h  = blockIdx.x & 7;
  int n0 = (int)(blockIdx.x >> 3) * 64;
  int j  = threadIdx.x & 63;       // dim within head
  int w  = threadIdx.x >> 6;       // wave = row group
  #pragma unroll
  for (int i = 0; i < 16; i++) {
    int n = n0 + w * 16 + i;
    float val = v[(size_t)n * CC + h * DH + j];
    float ss = val * val;
    #pragma unroll
    for (int off = 32; off >= 1; off >>= 1) ss += __shfl_xor(ss, off, 64);
    float inv = 1.0f / (sqrtf(ss) + 1e-8f);
    unsigned short un = f2b(val * inv);
    tileV[j][w * 16 + i] = f2b(val);
    tileN[j][w * 16 + i] = un;
    vnfull[(size_t)n * CC + h * DH + j] = un;
    __builtin_nontemporal_store(val, out + (size_t)n * (2 * CC) + CC + h * DH + j);
  }
  __syncthreads();
  #pragma unroll
  for (int i = 0; i < 16; i++) {
    int jj = w * 16 + i;
    __builtin_nontemporal_store(tileV[jj][j], vT + ((size_t)h * DH + jj) * NN + n0 + j);
  }
  // G_h partial: G[d][k] += sum_{m in tile} V[m][d]*vn[m][k]
  int lane = threadIdx.x & 63, quad = lane >> 4, l16 = lane & 15;
  short8 aV[2];
  #pragma unroll
  for (int kh = 0; kh < 2; kh++)
    aV[kh] = *(const short8*)&tileV[w * 16 + l16][kh * 32 + quad * 8];
  #pragma unroll
  for (int ct = 0; ct < 4; ct++) {
    f32x4 g4 = (f32x4){0.f, 0.f, 0.f, 0.f};
    #pragma unroll
    for (int kh = 0; kh < 2; kh++) {
      short8 bN = *(const short8*)&tileN[ct * 16 + l16][kh * 32 + quad * 8];
      g4 = __builtin_amdgcn_mfma_f32_16x16x32_bf16(aV[kh], bN, g4, 0, 0, 0);
    }
    #pragma unroll
    for (int g = 0; g < 4; g++)
      atomicAdd(&Gf[(size_t)h * 4096 + (w * 16 + quad * 4 + g) * 64 + ct * 16 + l16], g4[g]);
  }
}

// ---------------------------------------------------------------------------
// k_rgemm: R = (1/8) vnfull.vnfull^T, 128x128 tiles, BK=32 dbuf staging
// (32 KB LDS), swizzled bank-balanced layout. Epilogue: signed-e bf16 Rg via
// NON-TEMPORAL stores (no Z/E here - k_fused row-sums Rg). grid 625.
__global__ __launch_bounds__(256) void k_rgemm(const unsigned short* __restrict__ vnfull,
                                               unsigned short* __restrict__ Rg) {
  __shared__ __align__(16) unsigned short As[2][4096];   // 16 KB (128 x 32 x2)
  __shared__ __align__(16) unsigned short Bs[2][4096];   // 16 KB
  int bi = (int)blockIdx.x % 25, bj = (int)blockIdx.x / 25;
  int n0 = bi * 128, m0 = bj * 128;
  int tid = threadIdx.x;
  int wv = tid >> 6, wr = wv >> 1, wc = wv & 1;
  int lane = tid & 63, quad = lane >> 4, l16 = lane & 15;

  const unsigned short* aG[2];
  const unsigned short* bG[2];
  int sl[2];
  #pragma unroll
  for (int t = 0; t < 2; t++) {
    int s = tid + t * 256;
    sl[t] = s;
    int row = ((s >> 5) << 3) | (s & 7), kc = (s >> 3) & 3;
    aG[t] = vnfull + (size_t)(n0 + row) * CC + kc * 8;
    bG[t] = vnfull + (size_t)(m0 + row) * CC + kc * 8;
  }

  int roA[4], roB[4];
  #pragma unroll
  for (int rt = 0; rt < 4; rt++) {
    int row = wr * 64 + rt * 16 + l16;
    roA[rt] = (row >> 3) * 256 + (row & 7) * 8;
  }
  #pragma unroll
  for (int ct = 0; ct < 4; ct++) {
    int row = wc * 64 + ct * 16 + l16;
    roB[ct] = (row >> 3) * 256 + (row & 7) * 8;
  }

  f32x4 acc[4][4];
  #pragma unroll
  for (int rt = 0; rt < 4; rt++)
    #pragma unroll
    for (int ct = 0; ct < 4; ct++) acc[rt][ct] = (f32x4){0.f, 0.f, 0.f, 0.f};

  #pragma unroll
  for (int t = 0; t < 2; t++) gl_lds16(aG[t], &As[0][sl[t] * 8]);
  #pragma unroll
  for (int t = 0; t < 2; t++) gl_lds16(bG[t], &Bs[0][sl[t] * 8]);
  __syncthreads();

  #pragma unroll 1
  for (int kk = 0; kk < 16; kk++) {
    int buf = kk & 1;
    if (kk < 15) {
      int ko = (kk + 1) * 32;
      #pragma unroll
      for (int t = 0; t < 2; t++) gl_lds16(aG[t] + ko, &As[buf ^ 1][sl[t] * 8]);
      #pragma unroll
      for (int t = 0; t < 2; t++) gl_lds16(bG[t] + ko, &Bs[buf ^ 1][sl[t] * 8]);
    }
    short8 af[4], bf[4];
    #pragma unroll
    for (int rt = 0; rt < 4; rt++)
      af[rt] = *(const short8*)&As[buf][roA[rt] + quad * 64];
    #pragma unroll
    for (int ct = 0; ct < 4; ct++)
      bf[ct] = *(const short8*)&Bs[buf][roB[ct] + quad * 64];
    #pragma unroll
    for (int rt = 0; rt < 4; rt++)
      #pragma unroll
      for (int ct = 0; ct < 4; ct++)
        acc[rt][ct] = __builtin_amdgcn_mfma_f32_16x16x32_bf16(af[rt], bf[ct],
                                                              acc[rt][ct], 0, 0, 0);
    __syncthreads();
  }

  // ---- epilogue: signed-e, non-temporal scatter (L2 coalesces rows) ------
  #pragma unroll
  for (int rt = 0; rt < 4; rt++) {
    int nbase = n0 + wr * 64 + rt * 16 + quad * 4;
    #pragma unroll
    for (int g = 0; g < 4; g++) {
      int n = nbase + g;
      int bs = (n / 10) * 10;
      #pragma unroll
      for (int ct = 0; ct < 4; ct++) {
        int m = m0 + wc * 64 + ct * 16 + l16;
        float R = acc[rt][ct][g] * 0.125f;
        float eR = __expf(R);
        bool sel = (R > 0.75f);
        bool zz = (m >= bs) & (m < bs + 9) & (m != n);
        float ef = zz ? 1.0f : eR;            // exp(0)=1
        __builtin_nontemporal_store(f2b(sel ? ef : -ef), Rg + (size_t)n * NN + m);
      }
    }
  }
}

// ---------------------------------------------------------------------------
// k_fused: blocks [0,800): out2 rows (wave-per-row Z/E sum + normalize);
//          blocks [800,1200): k_x tiles (X = vn.G - zone corr).
__global__ __launch_bounds__(256) void k_fused(const unsigned short* __restrict__ Rg,
                                               const unsigned short* __restrict__ vnfull,
                                               const float* __restrict__ Gf,
                                               const unsigned short* __restrict__ vT,
                                               float* __restrict__ out2,
                                               float* __restrict__ out) {
  int bid = (int)blockIdx.x;
  if (bid < 800) {
    // ---- softmax rows: n = bid*4 + wave ---------------------------------
    int w = threadIdx.x >> 6, lane = threadIdx.x & 63;
    int n = bid * 4 + w;
    const unsigned short* rp = Rg + (size_t)n * NN;
    short8 s[7];
    float z = 0.f, e = 0.f;
    #pragma unroll
    for (int i = 0; i < 7; i++) {
      int c = lane + i * 64;              // chunk of 8 bf16; 400 chunks/row
      if (c < 400) {
        s[i] = __builtin_nontemporal_load((const short8*)(rp + c * 8));
        #pragma unroll
        for (int j = 0; j < 8; j++) {
          float val = b2f((unsigned short)s[i][j]);
          z += fabsf(val);
          e += fmaxf(val, 0.f);
        }
      }
    }
    #pragma unroll
    for (int off = 1; off <= 32; off <<= 1) {
      z += __shfl_xor(z, off, 64);
      e += __shfl_xor(e, off, 64);
    }
    float rd = 1.0f / (e + 1e-8f * z);
    float* op = out2 + (size_t)n * NN;
    #pragma unroll
    for (int i = 0; i < 7; i++) {
      int c = lane + i * 64;
      if (c < 400) {
        f32x4 o0, o1;
        #pragma unroll
        for (int j = 0; j < 4; j++) {
          float a = b2f((unsigned short)s[i][j]);
          o0[j] = (a > 0.f) ? a * rd : 0.f;
          float b = b2f((unsigned short)s[i][4 + j]);
          o1[j] = (b > 0.f) ? b * rd : 0.f;
        }
        __builtin_nontemporal_store(o0, (f32x4*)(op + c * 8));
        __builtin_nontemporal_store(o1, (f32x4*)(op + c * 8 + 4));
      }
    }
  } else {
    // ---- X tiles: X_h[n][d] = vn.G - zone correction --------------------
    bid -= 800;
    __shared__ __align__(16) unsigned short Sz[4][16][48];
    int hl   = threadIdx.x >> 6;
    int h    = (bid & 1) * 4 + hl;
    int lane = threadIdx.x & 63;
    int quad = lane >> 4, l16 = lane & 15;
    int n0 = (bid >> 1) * 16;
    int lo = (n0 / 10) * 10;                    // zone window [lo, lo+32)

    short8 aZ[2];
    #pragma unroll
    for (int kh = 0; kh < 2; kh++)
      aZ[kh] = *(const short8*)(vnfull + (size_t)(n0 + l16) * CC + h * DH + kh * 32 + quad * 8);

    #pragma unroll
    for (int ct = 0; ct < 2; ct++) {
      int rB = lo + ct * 16 + l16;
      int rC = rB < NN ? rB : NN - 1;           // clamp OOB (mask kills it)
      short8 b0 = *(const short8*)(vnfull + (size_t)rC * CC + h * DH + quad * 8);
      short8 b1 = *(const short8*)(vnfull + (size_t)rC * CC + h * DH + 32 + quad * 8);
      f32x4 cS = (f32x4){0.f, 0.f, 0.f, 0.f};
      cS = __builtin_amdgcn_mfma_f32_16x16x32_bf16(aZ[0], b0, cS, 0, 0, 0);
      cS = __builtin_amdgcn_mfma_f32_16x16x32_bf16(aZ[1], b1, cS, 0, 0, 0);
      int m = lo + ct * 16 + l16;
      #pragma unroll
      for (int g = 0; g < 4; g++) {
        int n = n0 + quad * 4 + g;
        int bs = (n / 10) * 10;
        bool keep = (m >= bs) & (m < bs + 9) & (m != n);
        Sz[hl][quad * 4 + g][ct * 16 + l16] = f2b(keep ? -cS[g] : 0.f);
      }
    }
    __syncthreads();

    f32x4 xr[4];
    #pragma unroll
    for (int nt = 0; nt < 4; nt++) {
      const float* gp = Gf + (size_t)h * 4096 + (nt * 16 + l16) * 64 + quad * 8;
      short8 g0 = pack8(*(const f32x4*)gp, *(const f32x4*)(gp + 4));
      short8 g1 = pack8(*(const f32x4*)(gp + 32), *(const f32x4*)(gp + 36));
      f32x4 cX = (f32x4){0.f, 0.f, 0.f, 0.f};
      cX = __builtin_amdgcn_mfma_f32_16x16x32_bf16(aZ[0], g0, cX, 0, 0, 0);
      cX = __builtin_amdgcn_mfma_f32_16x16x32_bf16(aZ[1], g1, cX, 0, 0, 0);
      xr[nt] = cX;
    }

    short8 aC = *(const short8*)&Sz[hl][l16][quad * 8];
    #pragma unroll
    for (int nt = 0; nt < 4; nt++) {
      short8 b = *(const short8*)(vT + (size_t)(h * DH + nt * 16 + l16) * NN + lo + quad * 8);
      xr[nt] = __builtin_amdgcn_mfma_f32_16x16x32_bf16(aC, b, xr[nt], 0, 0, 0);
    }

    #pragma unroll
    for (int nt = 0; nt < 4; nt++)
      #pragma unroll
      for (int g = 0; g < 4; g++)
        __builtin_nontemporal_store(xr[nt][g],
            out + (size_t)(n0 + quad * 4 + g) * (2 * CC) + h * DH + nt * 16 + l16);
  }
}

// ---------------------------------------------------------------------------
extern "C" void kernel_launch(void* const* d_in, const int* in_sizes, int n_in,
                              void* d_out, int out_size, void* d_ws, size_t ws_size,
                              hipStream_t stream) {
  const float* v = (const float*)d_in[1];   // only live input
  float* out = (float*)d_out;

  // ws carve (~27 MB): [Gf 32768] f32, [vnfull][vT] bf16, [Rg] bf16
  float* Gf = (float*)d_ws;
  unsigned short* vnfull = (unsigned short*)(Gf + HEADS * DH * DH);
  unsigned short* vT = vnfull + (size_t)NN * CC;
  unsigned short* Rg = vT + (size_t)NN * CC;

  hipMemsetAsync(Gf, 0, HEADS * DH * DH * sizeof(float), stream);
  k_prep<<<dim3(HEADS * (NN / 64)), dim3(256), 0, stream>>>(v, vnfull, vT, Gf, out);
  k_rgemm<<<dim3(25 * 25), dim3(256), 0, stream>>>(vnfull, Rg);
  k_fused<<<dim3(800 + (NN / 16) * 2), dim3(256), 0, stream>>>(
      Rg, vnfull, Gf, vT, out + (size_t)NN * 2 * CC, out);
}